// Round 7
// baseline (479.392 us; speedup 1.0000x reference)
//
#include <hip/hip_runtime.h>
#include <hip/hip_bf16.h>
#include <hip/hip_fp16.h>
#include <math.h>

#define NN 50000
#define EE 800000
#define E2K 400000
#define DINK 512
#define DHK 128
#define CK 8
#define KIT 5
#define NBLKS 196  // ceil(NN/256)
#define EPT 4      // edges per thread in msg_kernel; all gathers issued upfront

typedef __attribute__((ext_vector_type(8))) short short8;
typedef __attribute__((ext_vector_type(4))) float f32x4;

__device__ __forceinline__ unsigned short f2bf(float f) {
    union { float f; unsigned int u; } v;
    v.f = f;
    unsigned int u = v.u;
    unsigned int r = (u + 0x7FFFu + ((u >> 16) & 1u)) >> 16;  // RNE
    return (unsigned short)r;
}
__device__ __forceinline__ float bfu2f(unsigned int lo16) {
    union { unsigned int u; float f; } v;
    v.u = lo16 << 16;
    return v.f;
}

// merged prep: blocks 0..255 transpose W1 -> bf16 W1t; block 256 computes
// logH; blocks 257+ zero cnt.
__global__ __launch_bounds__(256) void prep_kernel(
    const float* __restrict__ W1, const float* __restrict__ param,
    unsigned short* __restrict__ W1t, float* __restrict__ logH,
    int* __restrict__ cnt) {
    if (blockIdx.x < 256) {
        int idx = blockIdx.x * 256 + threadIdx.x;  // 65536
        int n = idx >> 9;
        int k = idx & 511;
        W1t[idx] = f2bf(W1[(size_t)k * DHK + n]);
    } else if (blockIdx.x == 256) {
        if (threadIdx.x < 64) {
            int t = threadIdx.x;
            int i = t >> 3, j = t & 7;
            float z = param[i * 8 + j] + param[j * 8 + i];
            logH[t] = fminf(z, 0.0f) - log1pf(expf(-fabsf(z)));
        }
    } else {
        int i = (blockIdx.x - 257) * 256 + threadIdx.x;
        if (i < NN) cnt[i] = 0;
    }
}

// ---- MFMA MLP (R0-proven binary: VGPR 100, ~70us; source kept as-is) ----
__device__ __forceinline__ void mlp_load(const float* const* xptr,
                                         const unsigned short* const* bptr,
                                         int koff, float4 (&ar)[4][2],
                                         short8 (&bc)[4]) {
#pragma unroll
    for (int mt = 0; mt < 4; ++mt) {
        ar[mt][0] = *(const float4*)(xptr[mt] + koff);
        ar[mt][1] = *(const float4*)(xptr[mt] + koff + 4);
    }
#pragma unroll
    for (int nt = 0; nt < 4; ++nt) bc[nt] = *(const short8*)(bptr[nt] + koff);
}

__device__ __forceinline__ void mlp_step(const float4 (&ar)[4][2],
                                         const short8 (&bc)[4],
                                         f32x4 (&acc)[4][4]) {
    short8 af[4];
#pragma unroll
    for (int mt = 0; mt < 4; ++mt) {
        union { short8 s; __hip_bfloat162 h[4]; } cv;
        cv.h[0] = __float22bfloat162_rn(make_float2(ar[mt][0].x, ar[mt][0].y));
        cv.h[1] = __float22bfloat162_rn(make_float2(ar[mt][0].z, ar[mt][0].w));
        cv.h[2] = __float22bfloat162_rn(make_float2(ar[mt][1].x, ar[mt][1].y));
        cv.h[3] = __float22bfloat162_rn(make_float2(ar[mt][1].z, ar[mt][1].w));
        af[mt] = cv.s;
    }
#pragma unroll
    for (int mt = 0; mt < 4; ++mt)
#pragma unroll
        for (int nt = 0; nt < 4; ++nt)
            acc[mt][nt] = __builtin_amdgcn_mfma_f32_16x16x32_bf16(
                af[mt], bc[nt], acc[mt][nt], 0, 0, 0);
}

__global__ __launch_bounds__(256) void mlp_mfma_kernel(
    const float* __restrict__ x, const unsigned short* __restrict__ W1t,
    const float* __restrict__ b1, const float* __restrict__ W2,
    const float* __restrict__ b2, float* __restrict__ logb0) {
    __shared__ unsigned short hs[128 * 136];
    __shared__ float W2s[128 * 8];
    __shared__ float b1s[128];
    __shared__ float b2s[8];

    const int tid = threadIdx.x;
    const int wave = tid >> 6;
    const int lane = tid & 63;
    const int q = lane >> 4;
    const int lm = lane & 15;
    const int wm = wave >> 1, wn = wave & 1;
    const int n0 = blockIdx.x * 128;

    if (tid < 128) b1s[tid] = b1[tid];
    if (tid < 8) b2s[tid] = b2[tid];
    {
        int i = tid * 4;
        *(float4*)&W2s[i] = *(const float4*)&W2[i];
    }
    __syncthreads();

    const float* xptr[4];
#pragma unroll
    for (int mt = 0; mt < 4; ++mt) {
        int r = n0 + wm * 64 + mt * 16 + lm;
        if (r > NN - 1) r = NN - 1;
        xptr[mt] = x + (size_t)r * DINK + q * 8;
    }
    const unsigned short* bptr[4];
#pragma unroll
    for (int nt = 0; nt < 4; ++nt) {
        int c = wn * 64 + nt * 16 + lm;
        bptr[nt] = W1t + (size_t)c * DINK + q * 8;
    }

    f32x4 acc[4][4];
#pragma unroll
    for (int mt = 0; mt < 4; ++mt)
#pragma unroll
        for (int nt = 0; nt < 4; ++nt) acc[mt][nt] = (f32x4){0.f, 0.f, 0.f, 0.f};

    float4 arA[4][2], arB[4][2];
    short8 bcA[4], bcB[4];
    mlp_load(xptr, bptr, 0, arA, bcA);
    mlp_load(xptr, bptr, 32, arB, bcB);

#pragma unroll
    for (int k0 = 0; k0 < DINK; k0 += 64) {
        mlp_step(arA, bcA, acc);
        if (k0 + 64 < DINK) mlp_load(xptr, bptr, k0 + 64, arA, bcA);
        mlp_step(arB, bcB, acc);
        if (k0 + 96 < DINK) mlp_load(xptr, bptr, k0 + 96, arB, bcB);
    }

#pragma unroll
    for (int nt = 0; nt < 4; ++nt) {
        int j = wn * 64 + nt * 16 + lm;
        float bj = b1s[j];
#pragma unroll
        for (int mt = 0; mt < 4; ++mt) {
            int rbase = wm * 64 + mt * 16 + q * 4;
#pragma unroll
            for (int r = 0; r < 4; ++r) {
                float h = fmaxf(acc[mt][nt][r] + bj, 0.0f);
                hs[(rbase + r) * 136 + j] = f2bf(h);
            }
        }
    }
    __syncthreads();

    int row = tid >> 1;
    int half = tid & 1;
    const unsigned short* hp = &hs[row * 136 + half * 64];
    float p[8] = {0.f, 0.f, 0.f, 0.f, 0.f, 0.f, 0.f, 0.f};
#pragma unroll
    for (int ch = 0; ch < 8; ++ch) {
        uint4 c4 = *(const uint4*)(hp + ch * 8);
        unsigned int uu[4] = {c4.x, c4.y, c4.z, c4.w};
#pragma unroll
        for (int p2 = 0; p2 < 4; ++p2) {
            float h0 = bfu2f(uu[p2] & 0xFFFFu);
            float h1 = bfu2f(uu[p2] >> 16);
            int j = half * 64 + ch * 8 + p2 * 2;
            const float* w0 = &W2s[j * 8];
            const float* w1 = &W2s[(j + 1) * 8];
#pragma unroll
            for (int c = 0; c < 8; ++c) p[c] = fmaf(h0, w0[c], p[c]);
#pragma unroll
            for (int c = 0; c < 8; ++c) p[c] = fmaf(h1, w1[c], p[c]);
        }
    }
#pragma unroll
    for (int c = 0; c < 8; ++c) p[c] += __shfl_xor(p[c], 1, 64);
    int grow = n0 + row;
    if (half == 0 && grow < NN) {
        float v[8];
        float mx = -1e30f;
#pragma unroll
        for (int c = 0; c < 8; ++c) {
            v[c] = p[c] + b2s[c];
            mx = fmaxf(mx, v[c]);
        }
        float s = 0.0f;
#pragma unroll
        for (int c = 0; c < 8; ++c) s += expf(v[c] - mx);
        float ln = mx + logf(s);
        float4* p0 = (float4*)&logb0[(size_t)grow * 8];
        p0[0] = make_float4(v[0] - ln, v[1] - ln, v[2] - ln, v[3] - ln);
        p0[1] = make_float4(v[4] - ln, v[5] - ln, v[6] - ln, v[7] - ln);
    }
}

// ---------------- CSR setup ----------------

__global__ __launch_bounds__(256) void deg_pair_kernel(const int* __restrict__ ei,
                                                       int* __restrict__ cnt) {
    int e = blockIdx.x * 256 + threadIdx.x;
    if (e >= E2K) return;
    int s = ei[e];
    int d = ei[EE + e];
    atomicAdd(&cnt[d], 1);
    atomicAdd(&cnt[s], 1);
}

__global__ __launch_bounds__(256) void scan_partial_kernel(
    const int* __restrict__ cnt, int* __restrict__ partial) {
    __shared__ int sd[256];
    int t = threadIdx.x;
    int i = blockIdx.x * 256 + t;
    sd[t] = (i < NN) ? cnt[i] : 0;
    __syncthreads();
#pragma unroll
    for (int s = 128; s > 0; s >>= 1) {
        if (t < s) sd[t] += sd[t + s];
        __syncthreads();
    }
    if (t == 0) partial[blockIdx.x] = sd[0];
}

__global__ __launch_bounds__(256) void scan_write2_kernel(
    const int* __restrict__ cnt, const int* __restrict__ partial,
    int* __restrict__ off, int* __restrict__ cnt_z) {
    __shared__ int sd[256];
    const int t = threadIdx.x;
    const int b = blockIdx.x;
    sd[t] = (t < NBLKS) ? partial[t] : 0;
    __syncthreads();
#pragma unroll
    for (int s = 1; s < 256; s <<= 1) {
        int a = sd[t];
        int v = (t >= s) ? sd[t - s] : 0;
        __syncthreads();
        sd[t] = a + v;
        __syncthreads();
    }
    const int top = (b > 0) ? sd[b - 1] : 0;
    __syncthreads();
    int i = b * 256 + t;
    int v = (i < NN) ? cnt[i] : 0;
    sd[t] = v;
    __syncthreads();
#pragma unroll
    for (int s = 1; s < 256; s <<= 1) {
        int a = sd[t];
        int w = (t >= s) ? sd[t - s] : 0;
        __syncthreads();
        sd[t] = a + w;
        __syncthreads();
    }
    if (i < NN) {
        off[i] = top + sd[t] - v;
        cnt_z[i] = 0;
    }
    if (i == NN - 1) off[NN] = EE;
}

// rw[j] = (rvp, wbits): reverse-edge permuted index + weight, one 8B header.
__global__ __launch_bounds__(256) void pos_pair_kernel(
    const int* __restrict__ ei, const float* __restrict__ ew,
    const int* __restrict__ off, int* __restrict__ cnt,
    int2* __restrict__ rw) {
    int e = blockIdx.x * 256 + threadIdx.x;
    if (e >= E2K) return;
    int s = ei[e];
    int d = ei[EE + e];
    int wbits = __float_as_int(ew[e]);
    int pA = off[d] + atomicAdd(&cnt[d], 1);  // edge e: s->d
    int pB = off[s] + atomicAdd(&cnt[s], 1);  // edge e+E2: d->s
    int2 v;
    v.x = pB; v.y = wbits; rw[pA] = v;
    v.x = pA;              rw[pB] = v;
}

// z[j] = logb0[dst(j)] for iteration 0 (contiguous per CSR slice).
__global__ __launch_bounds__(256) void zinit_kernel(
    const float* __restrict__ logb0, const int* __restrict__ off,
    _Float16* __restrict__ z) {
    const int t = threadIdx.x;
    const int n = blockIdx.x * 32 + (t >> 3);
    const int c = t & 7;
    if (n >= NN) return;
    _Float16 v = (_Float16)logb0[(size_t)n * 8 + c];
    const int j0 = off[n];
    const int j1 = off[n + 1];
    for (int j = j0; j < j1; ++j) z[(size_t)j * 8 + c] = v;
}

// ---------------- BP iteration ----------------
// msg: xin[j] = z[rvp[j]] — the ONLY random access (16B gather, EPT issued
// upfront for 4 outstanding lines/thread). Messages written unnormalized.
__global__ __launch_bounds__(256) void msg_kernel(
    const int2* __restrict__ rw, const float* __restrict__ logH,
    const uint4* __restrict__ zbuf, uint4* __restrict__ msg_next) {
    __shared__ float lH[64];
    const int t = threadIdx.x;
    if (t < 64) lH[t] = logH[t];
    __syncthreads();

    const int base = blockIdx.x * (256 * EPT) + t;

    int2 h[EPT];
#pragma unroll
    for (int e = 0; e < EPT; ++e) {
        int j = base + e * 256;
        int jc = (j < EE) ? j : (EE - 1);
        h[e] = rw[jc];
    }
    uint4 zv[EPT];
#pragma unroll
    for (int e = 0; e < EPT; ++e) zv[e] = zbuf[h[e].x];  // all gathers issued

#pragma unroll
    for (int e = 0; e < EPT; ++e) {
        float w = __int_as_float(h[e].y);
        union { uint4 u; _Float16 hh[8]; } cv;
        cv.u = zv[e];
        float xj[8];
#pragma unroll
        for (int k = 0; k < 8; ++k) xj[k] = (float)cv.hh[k];
        float mg[8];
#pragma unroll
        for (int c2 = 0; c2 < 8; ++c2) {
            float ssum = 0.0f;
#pragma unroll
            for (int c1 = 0; c1 < 8; ++c1)
                ssum += __expf(fmaf(w, lH[c1 * 8 + c2], xj[c1]));
            mg[c2] = __logf(ssum);
        }
        union { uint4 u; _Float16 hh[8]; } ov;
#pragma unroll
        for (int k = 0; k < 8; ++k) ov.hh[k] = (_Float16)mg[k];
        int j = base + e * 256;
        if (j < EE) msg_next[j] = ov.u;
    }
}

// agg: belief + NEXT-ITER z slice (contiguous). No bel array at all.
__global__ __launch_bounds__(256) void agg_kernel(
    const float* __restrict__ logb0, const int* __restrict__ off,
    const uint4* __restrict__ msg, _Float16* __restrict__ z,
    float* __restrict__ out, int last) {
    const int t = threadIdx.x;
    const int n = blockIdx.x * 32 + (t >> 3);
    const int c = t & 7;
    if (n >= NN) return;
    float a = logb0[(size_t)n * 8 + c];
    const int j0 = off[n];
    const int j1 = off[n + 1];
    const _Float16* mh = (const _Float16*)msg;
    float s0 = 0.f, s1 = 0.f, s2 = 0.f, s3 = 0.f;
    int j = j0;
    for (; j + 4 <= j1; j += 4) {
        s0 += (float)mh[(size_t)(j + 0) * 8 + c];
        s1 += (float)mh[(size_t)(j + 1) * 8 + c];
        s2 += (float)mh[(size_t)(j + 2) * 8 + c];
        s3 += (float)mh[(size_t)(j + 3) * 8 + c];
    }
    for (; j < j1; ++j) s0 += (float)mh[(size_t)j * 8 + c];
    a += (s0 + s1) + (s2 + s3);
    float mx = a;
#pragma unroll
    for (int s = 1; s < 8; s <<= 1) mx = fmaxf(mx, __shfl_xor(mx, s, 8));
    float sum = __expf(a - mx);
#pragma unroll
    for (int s = 1; s < 8; s <<= 1) sum += __shfl_xor(sum, s, 8);
    float v = a - (mx + __logf(sum));
    if (last) {
        out[(size_t)n * 8 + c] = v;
    } else {
        // z[j] = bel[n] - msg[j] for this node's slice (contiguous, L1-hot)
        for (int jj = j0; jj < j1; ++jj)
            z[(size_t)jj * 8 + c] = (_Float16)(v - (float)mh[(size_t)jj * 8 + c]);
    }
}

extern "C" void kernel_launch(void* const* d_in, const int* in_sizes, int n_in,
                              void* d_out, int out_size, void* d_ws, size_t ws_size,
                              hipStream_t stream) {
    const float* x = (const float*)d_in[0];
    const int* ei = (const int*)d_in[1];
    const float* ew = (const float*)d_in[2];
    const float* W1 = (const float*)d_in[4];
    const float* b1 = (const float*)d_in[5];
    const float* W2 = (const float*)d_in[6];
    const float* b2 = (const float*)d_in[7];
    const float* param = (const float*)d_in[8];
    float* out = (float*)d_out;

    float* wsf = (float*)d_ws;
    float* logH = wsf;                                  // 64 f
    float* logb0 = logH + 64;                           // 400000 f
    uint4* msgbuf = (uint4*)(logb0 + (size_t)NN * 8);   // 12.8 MB
    uint4* zbuf = msgbuf + EE;                          // 12.8 MB
    int* off = (int*)(zbuf + EE);                       // padded to 50004 ints
    int2* rw = (int2*)(off + 50004);                    // 800000 int2
    unsigned short* W1t = (unsigned short*)(rw + EE);   // 65536 bf16
    // setup-only scratch aliases msgbuf (first written by msg iter 0)
    int* cnt = (int*)msgbuf;                            // 50000
    int* partial = cnt + NN;                            // 196

    const int ZB = (NN + 255) / 256;  // cnt-zero blocks in prep
    prep_kernel<<<257 + ZB, 256, 0, stream>>>(W1, param, W1t, logH, cnt);
    mlp_mfma_kernel<<<(NN + 127) / 128, 256, 0, stream>>>(x, W1t, b1, W2, b2,
                                                          logb0);

    const int E2B = (E2K + 255) / 256;
    deg_pair_kernel<<<E2B, 256, 0, stream>>>(ei, cnt);
    scan_partial_kernel<<<NBLKS, 256, 0, stream>>>(cnt, partial);
    scan_write2_kernel<<<NBLKS, 256, 0, stream>>>(cnt, partial, off, cnt);
    pos_pair_kernel<<<E2B, 256, 0, stream>>>(ei, ew, off, cnt, rw);

    const int AB = (NN + 31) / 32;  // node-parallel grids (zinit, agg)
    zinit_kernel<<<AB, 256, 0, stream>>>(logb0, off, (_Float16*)zbuf);

    const int MB = (EE + 256 * EPT - 1) / (256 * EPT);  // 782 blocks
    for (int it = 0; it < KIT; ++it) {
        msg_kernel<<<MB, 256, 0, stream>>>(rw, logH, zbuf, msgbuf);
        agg_kernel<<<AB, 256, 0, stream>>>(logb0, off, msgbuf,
                                           (_Float16*)zbuf, out,
                                           it == KIT - 1 ? 1 : 0);
    }
}

// Round 9
// 419.752 us; speedup vs baseline: 1.1421x; 1.1421x over previous
//
#include <hip/hip_runtime.h>
#include <hip/hip_bf16.h>
#include <hip/hip_fp16.h>
#include <math.h>

#define NN 50000
#define EE 800000
#define E2K 400000
#define DINK 512
#define DHK 128
#define CK 8
#define KIT 5
#define NBLKS 196  // ceil(NN/256)
#define NPB 32     // nodes per bp block
#define CAP 1024   // LDS message cache (edges); mean block edges ~512

typedef __attribute__((ext_vector_type(8))) short short8;
typedef __attribute__((ext_vector_type(4))) float f32x4;

__device__ __forceinline__ unsigned short f2bf(float f) {
    union { float f; unsigned int u; } v;
    v.f = f;
    unsigned int u = v.u;
    unsigned int r = (u + 0x7FFFu + ((u >> 16) & 1u)) >> 16;  // RNE
    return (unsigned short)r;
}
__device__ __forceinline__ float bfu2f(unsigned int lo16) {
    union { unsigned int u; float f; } v;
    v.u = lo16 << 16;
    return v.f;
}

// merged prep: blocks 0..255 transpose W1 -> bf16 W1t; block 256 computes
// logH; blocks 257+ zero cnt.
__global__ __launch_bounds__(256) void prep_kernel(
    const float* __restrict__ W1, const float* __restrict__ param,
    unsigned short* __restrict__ W1t, float* __restrict__ logH,
    int* __restrict__ cnt) {
    if (blockIdx.x < 256) {
        int idx = blockIdx.x * 256 + threadIdx.x;  // 65536
        int n = idx >> 9;
        int k = idx & 511;
        W1t[idx] = f2bf(W1[(size_t)k * DHK + n]);
    } else if (blockIdx.x == 256) {
        if (threadIdx.x < 64) {
            int t = threadIdx.x;
            int i = t >> 3, j = t & 7;
            float z = param[i * 8 + j] + param[j * 8 + i];
            logH[t] = fminf(z, 0.0f) - log1pf(expf(-fabsf(z)));
        }
    } else {
        int i = (blockIdx.x - 257) * 256 + threadIdx.x;
        if (i < NN) cnt[i] = 0;
    }
}

// ---- MFMA MLP (R0-proven binary: VGPR 100, ~70us; source kept as-is) ----
__device__ __forceinline__ void mlp_load(const float* const* xptr,
                                         const unsigned short* const* bptr,
                                         int koff, float4 (&ar)[4][2],
                                         short8 (&bc)[4]) {
#pragma unroll
    for (int mt = 0; mt < 4; ++mt) {
        ar[mt][0] = *(const float4*)(xptr[mt] + koff);
        ar[mt][1] = *(const float4*)(xptr[mt] + koff + 4);
    }
#pragma unroll
    for (int nt = 0; nt < 4; ++nt) bc[nt] = *(const short8*)(bptr[nt] + koff);
}

__device__ __forceinline__ void mlp_step(const float4 (&ar)[4][2],
                                         const short8 (&bc)[4],
                                         f32x4 (&acc)[4][4]) {
    short8 af[4];
#pragma unroll
    for (int mt = 0; mt < 4; ++mt) {
        union { short8 s; __hip_bfloat162 h[4]; } cv;
        cv.h[0] = __float22bfloat162_rn(make_float2(ar[mt][0].x, ar[mt][0].y));
        cv.h[1] = __float22bfloat162_rn(make_float2(ar[mt][0].z, ar[mt][0].w));
        cv.h[2] = __float22bfloat162_rn(make_float2(ar[mt][1].x, ar[mt][1].y));
        cv.h[3] = __float22bfloat162_rn(make_float2(ar[mt][1].z, ar[mt][1].w));
        af[mt] = cv.s;
    }
#pragma unroll
    for (int mt = 0; mt < 4; ++mt)
#pragma unroll
        for (int nt = 0; nt < 4; ++nt)
            acc[mt][nt] = __builtin_amdgcn_mfma_f32_16x16x32_bf16(
                af[mt], bc[nt], acc[mt][nt], 0, 0, 0);
}

__global__ __launch_bounds__(256) void mlp_mfma_kernel(
    const float* __restrict__ x, const unsigned short* __restrict__ W1t,
    const float* __restrict__ b1, const float* __restrict__ W2,
    const float* __restrict__ b2, float* __restrict__ logb0) {
    __shared__ unsigned short hs[128 * 136];
    __shared__ float W2s[128 * 8];
    __shared__ float b1s[128];
    __shared__ float b2s[8];

    const int tid = threadIdx.x;
    const int wave = tid >> 6;
    const int lane = tid & 63;
    const int q = lane >> 4;
    const int lm = lane & 15;
    const int wm = wave >> 1, wn = wave & 1;
    const int n0 = blockIdx.x * 128;

    if (tid < 128) b1s[tid] = b1[tid];
    if (tid < 8) b2s[tid] = b2[tid];
    {
        int i = tid * 4;
        *(float4*)&W2s[i] = *(const float4*)&W2[i];
    }
    __syncthreads();

    const float* xptr[4];
#pragma unroll
    for (int mt = 0; mt < 4; ++mt) {
        int r = n0 + wm * 64 + mt * 16 + lm;
        if (r > NN - 1) r = NN - 1;
        xptr[mt] = x + (size_t)r * DINK + q * 8;
    }
    const unsigned short* bptr[4];
#pragma unroll
    for (int nt = 0; nt < 4; ++nt) {
        int c = wn * 64 + nt * 16 + lm;
        bptr[nt] = W1t + (size_t)c * DINK + q * 8;
    }

    f32x4 acc[4][4];
#pragma unroll
    for (int mt = 0; mt < 4; ++mt)
#pragma unroll
        for (int nt = 0; nt < 4; ++nt) acc[mt][nt] = (f32x4){0.f, 0.f, 0.f, 0.f};

    float4 arA[4][2], arB[4][2];
    short8 bcA[4], bcB[4];
    mlp_load(xptr, bptr, 0, arA, bcA);
    mlp_load(xptr, bptr, 32, arB, bcB);

#pragma unroll
    for (int k0 = 0; k0 < DINK; k0 += 64) {
        mlp_step(arA, bcA, acc);
        if (k0 + 64 < DINK) mlp_load(xptr, bptr, k0 + 64, arA, bcA);
        mlp_step(arB, bcB, acc);
        if (k0 + 96 < DINK) mlp_load(xptr, bptr, k0 + 96, arB, bcB);
    }

#pragma unroll
    for (int nt = 0; nt < 4; ++nt) {
        int j = wn * 64 + nt * 16 + lm;
        float bj = b1s[j];
#pragma unroll
        for (int mt = 0; mt < 4; ++mt) {
            int rbase = wm * 64 + mt * 16 + q * 4;
#pragma unroll
            for (int r = 0; r < 4; ++r) {
                float h = fmaxf(acc[mt][nt][r] + bj, 0.0f);
                hs[(rbase + r) * 136 + j] = f2bf(h);
            }
        }
    }
    __syncthreads();

    int row = tid >> 1;
    int half = tid & 1;
    const unsigned short* hp = &hs[row * 136 + half * 64];
    float p[8] = {0.f, 0.f, 0.f, 0.f, 0.f, 0.f, 0.f, 0.f};
#pragma unroll
    for (int ch = 0; ch < 8; ++ch) {
        uint4 c4 = *(const uint4*)(hp + ch * 8);
        unsigned int uu[4] = {c4.x, c4.y, c4.z, c4.w};
#pragma unroll
        for (int p2 = 0; p2 < 4; ++p2) {
            float h0 = bfu2f(uu[p2] & 0xFFFFu);
            float h1 = bfu2f(uu[p2] >> 16);
            int j = half * 64 + ch * 8 + p2 * 2;
            const float* w0 = &W2s[j * 8];
            const float* w1 = &W2s[(j + 1) * 8];
#pragma unroll
            for (int c = 0; c < 8; ++c) p[c] = fmaf(h0, w0[c], p[c]);
#pragma unroll
            for (int c = 0; c < 8; ++c) p[c] = fmaf(h1, w1[c], p[c]);
        }
    }
#pragma unroll
    for (int c = 0; c < 8; ++c) p[c] += __shfl_xor(p[c], 1, 64);
    int grow = n0 + row;
    if (half == 0 && grow < NN) {
        float v[8];
        float mx = -1e30f;
#pragma unroll
        for (int c = 0; c < 8; ++c) {
            v[c] = p[c] + b2s[c];
            mx = fmaxf(mx, v[c]);
        }
        float s = 0.0f;
#pragma unroll
        for (int c = 0; c < 8; ++c) s += expf(v[c] - mx);
        float ln = mx + logf(s);
        float4* p0 = (float4*)&logb0[(size_t)grow * 8];
        p0[0] = make_float4(v[0] - ln, v[1] - ln, v[2] - ln, v[3] - ln);
        p0[1] = make_float4(v[4] - ln, v[5] - ln, v[6] - ln, v[7] - ln);
    }
}

// ---------------- CSR setup ----------------

__global__ __launch_bounds__(256) void deg_pair_kernel(const int* __restrict__ ei,
                                                       int* __restrict__ cnt) {
    int e = blockIdx.x * 256 + threadIdx.x;
    if (e >= E2K) return;
    int s = ei[e];
    int d = ei[EE + e];
    atomicAdd(&cnt[d], 1);
    atomicAdd(&cnt[s], 1);
}

__global__ __launch_bounds__(256) void scan_partial_kernel(
    const int* __restrict__ cnt, int* __restrict__ partial) {
    __shared__ int sd[256];
    int t = threadIdx.x;
    int i = blockIdx.x * 256 + t;
    sd[t] = (i < NN) ? cnt[i] : 0;
    __syncthreads();
#pragma unroll
    for (int s = 128; s > 0; s >>= 1) {
        if (t < s) sd[t] += sd[t + s];
        __syncthreads();
    }
    if (t == 0) partial[blockIdx.x] = sd[0];
}

__global__ __launch_bounds__(256) void scan_write2_kernel(
    const int* __restrict__ cnt, const int* __restrict__ partial,
    int* __restrict__ off, int* __restrict__ cnt_z) {
    __shared__ int sd[256];
    const int t = threadIdx.x;
    const int b = blockIdx.x;
    sd[t] = (t < NBLKS) ? partial[t] : 0;
    __syncthreads();
#pragma unroll
    for (int s = 1; s < 256; s <<= 1) {
        int a = sd[t];
        int v = (t >= s) ? sd[t - s] : 0;
        __syncthreads();
        sd[t] = a + v;
        __syncthreads();
    }
    const int top = (b > 0) ? sd[b - 1] : 0;
    __syncthreads();
    int i = b * 256 + t;
    int v = (i < NN) ? cnt[i] : 0;
    sd[t] = v;
    __syncthreads();
#pragma unroll
    for (int s = 1; s < 256; s <<= 1) {
        int a = sd[t];
        int w = (t >= s) ? sd[t - s] : 0;
        __syncthreads();
        sd[t] = a + w;
        __syncthreads();
    }
    if (i < NN) {
        off[i] = top + sd[t] - v;
        cnt_z[i] = 0;
    }
    if (i == NN - 1) off[NN] = EE;
}

// merged: blocks [0,E2B) place edges (rw = (rvp, wbits)); blocks [E2B, ...)
// init z0[j] = fp16(logb0[dst(j)]) contiguously per CSR slice. Independent
// outputs, both only need `off` -> one dispatch.
__global__ __launch_bounds__(256) void pos_zinit_kernel(
    const int* __restrict__ ei, const float* __restrict__ ew,
    const int* __restrict__ off, int* __restrict__ cnt,
    int2* __restrict__ rw, const float* __restrict__ logb0,
    _Float16* __restrict__ z, int E2B) {
    const int t = threadIdx.x;
    if ((int)blockIdx.x < E2B) {
        int e = blockIdx.x * 256 + t;
        if (e >= E2K) return;
        int s = ei[e];
        int d = ei[EE + e];
        int wbits = __float_as_int(ew[e]);
        int pA = off[d] + atomicAdd(&cnt[d], 1);  // edge e: s->d
        int pB = off[s] + atomicAdd(&cnt[s], 1);  // edge e+E2: d->s
        int2 v;
        v.x = pB; v.y = wbits; rw[pA] = v;
        v.x = pA;              rw[pB] = v;
    } else {
        int b = blockIdx.x - E2B;
        int n = b * 32 + (t >> 3);
        int c = t & 7;
        if (n >= NN) return;
        _Float16 v = (_Float16)logb0[(size_t)n * 8 + c];
        int j0 = off[n];
        int j1 = off[n + 1];
        for (int j = j0; j < j1; ++j) z[(size_t)j * 8 + c] = v;
    }
}

// ---------------- fused BP iteration: ONE dispatch per iteration ------------
// Block owns nodes [n0,n0+NPB) and CSR edge range [off[n0],off[n0+NPB)).
// Messages: xin[j] = z_prev[rvp[j]] (the ONLY random access), mg computed
// UNNORMALIZED into LDS (never global). Aggregate per node from LDS,
// normalize, then write z_next[j] = bel[dst(j)] - mg[j] CONTIGUOUSLY
// (load-balanced via LDS j->local-node map built during aggregation).
__global__ __launch_bounds__(256) void bp_fused_kernel(
    const float* __restrict__ logb0, const int* __restrict__ off,
    const int2* __restrict__ rw, const float* __restrict__ logH,
    const uint4* __restrict__ zprev, _Float16* __restrict__ znext,
    float* __restrict__ out, int last) {
    __shared__ _Float16 smg[CAP * 8];   // 16 KB message cache
    __shared__ float sb[NPB * 8];       // beliefs
    __shared__ unsigned char dln[CAP];  // j-cb -> local node
    __shared__ float lH[64];
    const int t = threadIdx.x;
    if (t < 64) lH[t] = logH[t];

    const int n0 = blockIdx.x * NPB;
    const int nend = (n0 + NPB < NN) ? (n0 + NPB) : NN;
    const int jb0 = off[n0];
    const int jb1 = off[nend];
    const int nl = t >> 3;
    const int c = t & 7;
    const int n = n0 + nl;

    float a = 0.0f;
    int jn0 = 0, jn1 = 0;
    if (n < nend) {
        jn0 = off[n];
        jn1 = off[n + 1];
        a = logb0[(size_t)n * 8 + c];
    }
    __syncthreads();  // lH ready

    const int single = (jb1 - jb0) <= CAP;

    for (int cb = jb0; cb < jb1; cb += CAP) {
        int ce = (cb + CAP < jb1) ? (cb + CAP) : jb1;
        for (int j = cb + t; j < ce; j += 256) {
            int2 h = rw[j];
            uint4 zv = zprev[h.x];  // single random 16B gather
            float w = __int_as_float(h.y);
            union { uint4 u; _Float16 hh[8]; } cv;
            cv.u = zv;
            float xj[8];
#pragma unroll
            for (int k = 0; k < 8; ++k) xj[k] = (float)cv.hh[k];
            float mg[8];
#pragma unroll
            for (int c2 = 0; c2 < 8; ++c2) {
                float ssum = 0.0f;
#pragma unroll
                for (int c1 = 0; c1 < 8; ++c1)
                    ssum += __expf(fmaf(w, lH[c1 * 8 + c2], xj[c1]));
                mg[c2] = __logf(ssum);
            }
            union { uint4 u; _Float16 hh[8]; } ov;
#pragma unroll
            for (int k = 0; k < 8; ++k) ov.hh[k] = (_Float16)mg[k];
            *(uint4*)&smg[(j - cb) * 8] = ov.u;
        }
        __syncthreads();
        int lo = (jn0 > cb) ? jn0 : cb;
        int hi = (jn1 < ce) ? jn1 : ce;
        for (int j = lo; j < hi; ++j) {
            a += (float)smg[(j - cb) * 8 + c];
            if (c == 0) dln[j - cb] = (unsigned char)nl;
        }
        __syncthreads();  // protect smg before next chunk
    }

    // ---- normalize belief (8-thread groups) ----
    float mx = a;
#pragma unroll
    for (int s = 1; s < 8; s <<= 1) mx = fmaxf(mx, __shfl_xor(mx, s, 8));
    float sum = __expf(a - mx);
#pragma unroll
    for (int s = 1; s < 8; s <<= 1) sum += __shfl_xor(sum, s, 8);
    float v = a - (mx + __logf(sum));
    if (n < nend) {
        if (last) out[(size_t)n * 8 + c] = v;
        sb[nl * 8 + c] = v;
    }
    if (last) return;
    __syncthreads();

    // ---- z-write: contiguous, load-balanced over (edge, channel) items ----
    for (int cb = jb0; cb < jb1; cb += CAP) {
        int ce = (cb + CAP < jb1) ? (cb + CAP) : jb1;
        if (!single) {
            // rare path: recompute this chunk's messages + rebuild dln
            for (int j = cb + t; j < ce; j += 256) {
                int2 h = rw[j];
                uint4 zv = zprev[h.x];
                float w = __int_as_float(h.y);
                union { uint4 u; _Float16 hh[8]; } cv;
                cv.u = zv;
                float xj[8];
#pragma unroll
                for (int k = 0; k < 8; ++k) xj[k] = (float)cv.hh[k];
                float mg[8];
#pragma unroll
                for (int c2 = 0; c2 < 8; ++c2) {
                    float ssum = 0.0f;
#pragma unroll
                    for (int c1 = 0; c1 < 8; ++c1)
                        ssum += __expf(fmaf(w, lH[c1 * 8 + c2], xj[c1]));
                    mg[c2] = __logf(ssum);
                }
                union { uint4 u; _Float16 hh[8]; } ov;
#pragma unroll
                for (int k = 0; k < 8; ++k) ov.hh[k] = (_Float16)mg[k];
                *(uint4*)&smg[(j - cb) * 8] = ov.u;
            }
            if (c == 0) {
                int lo = (jn0 > cb) ? jn0 : cb;
                int hi = (jn1 < ce) ? jn1 : ce;
                for (int j = lo; j < hi; ++j) dln[j - cb] = (unsigned char)nl;
            }
            __syncthreads();
        }
        int items = (ce - cb) * 8;
        for (int item = t; item < items; item += 256) {
            int jr = item >> 3;
            int c2 = item & 7;
            int dl = dln[jr];
            znext[(size_t)(cb + jr) * 8 + c2] =
                (_Float16)(sb[dl * 8 + c2] - (float)smg[jr * 8 + c2]);
        }
        if (!single) __syncthreads();
    }
}

extern "C" void kernel_launch(void* const* d_in, const int* in_sizes, int n_in,
                              void* d_out, int out_size, void* d_ws, size_t ws_size,
                              hipStream_t stream) {
    const float* x = (const float*)d_in[0];
    const int* ei = (const int*)d_in[1];
    const float* ew = (const float*)d_in[2];
    const float* W1 = (const float*)d_in[4];
    const float* b1 = (const float*)d_in[5];
    const float* W2 = (const float*)d_in[6];
    const float* b2 = (const float*)d_in[7];
    const float* param = (const float*)d_in[8];
    float* out = (float*)d_out;

    float* wsf = (float*)d_ws;
    float* logH = wsf;                                 // 64 f
    float* logb0 = logH + 64;                          // 400000 f
    uint4* zA = (uint4*)(logb0 + (size_t)NN * 8);      // 12.8 MB
    uint4* zB = zA + EE;                               // 12.8 MB
    int* off = (int*)(zB + EE);                        // padded to 50004 ints
    int2* rw = (int2*)(off + 50004);                   // 800000 int2
    unsigned short* W1t = (unsigned short*)(rw + EE);  // 65536 bf16
    // setup-only scratch aliases zB (zB first written by bp iter 0; zA is
    // written by zinit which runs concurrently with pos -> must not alias zA)
    int* cnt = (int*)zB;                               // 50000
    int* partial = cnt + NN;                           // 196

    const int ZB_ = (NN + 255) / 256;  // cnt-zero blocks in prep
    prep_kernel<<<257 + ZB_, 256, 0, stream>>>(W1, param, W1t, logH, cnt);
    mlp_mfma_kernel<<<(NN + 127) / 128, 256, 0, stream>>>(x, W1t, b1, W2, b2,
                                                          logb0);

    const int E2B = (E2K + 255) / 256;  // 1563
    const int AB = (NN + 31) / 32;      // 1563
    deg_pair_kernel<<<E2B, 256, 0, stream>>>(ei, cnt);
    scan_partial_kernel<<<NBLKS, 256, 0, stream>>>(cnt, partial);
    scan_write2_kernel<<<NBLKS, 256, 0, stream>>>(cnt, partial, off, cnt);
    pos_zinit_kernel<<<E2B + AB, 256, 0, stream>>>(ei, ew, off, cnt, rw, logb0,
                                                   (_Float16*)zA, E2B);

    // z ping-pong: zinit->zA; it0 zA->zB; it1 zB->zA; ... it4 reads zA
    const int BB = (NN + NPB - 1) / NPB;  // 1563
    uint4* zs[2] = {zA, zB};
    for (int it = 0; it < KIT; ++it) {
        bp_fused_kernel<<<BB, 256, 0, stream>>>(
            logb0, off, rw, logH, zs[it & 1], (_Float16*)zs[(it + 1) & 1], out,
            it == KIT - 1 ? 1 : 0);
    }
}

// Round 10
// 406.148 us; speedup vs baseline: 1.1803x; 1.0335x over previous
//
#include <hip/hip_runtime.h>
#include <hip/hip_bf16.h>
#include <hip/hip_fp16.h>
#include <math.h>

#define NN 50000
#define EE 800000
#define E2K 400000
#define DINK 512
#define DHK 128
#define CK 8
#define KIT 5
#define NBLKS 196  // ceil(NN/256)
#define NPB 32     // nodes per bp block
#define CAP 1024   // LDS message cache (edges); mean block edges ~512
#define LOG2E 1.4426950408889634f
#define LN2 0.6931471805599453f

typedef __attribute__((ext_vector_type(8))) short short8;
typedef __attribute__((ext_vector_type(4))) float f32x4;

__device__ __forceinline__ unsigned short f2bf(float f) {
    union { float f; unsigned int u; } v;
    v.f = f;
    unsigned int u = v.u;
    unsigned int r = (u + 0x7FFFu + ((u >> 16) & 1u)) >> 16;  // RNE
    return (unsigned short)r;
}
__device__ __forceinline__ float bfu2f(unsigned int lo16) {
    union { unsigned int u; float f; } v;
    v.u = lo16 << 16;
    return v.f;
}

// merged prep: blocks 0..255 transpose W1 -> bf16 W1t; block 256 computes
// logH (PRE-SCALED to log2 units); blocks 257+ zero cnt.
__global__ __launch_bounds__(256) void prep_kernel(
    const float* __restrict__ W1, const float* __restrict__ param,
    unsigned short* __restrict__ W1t, float* __restrict__ logH,
    int* __restrict__ cnt) {
    if (blockIdx.x < 256) {
        int idx = blockIdx.x * 256 + threadIdx.x;  // 65536
        int n = idx >> 9;
        int k = idx & 511;
        W1t[idx] = f2bf(W1[(size_t)k * DHK + n]);
    } else if (blockIdx.x == 256) {
        if (threadIdx.x < 64) {
            int t = threadIdx.x;
            int i = t >> 3, j = t & 7;
            float z = param[i * 8 + j] + param[j * 8 + i];
            logH[t] = (fminf(z, 0.0f) - log1pf(expf(-fabsf(z)))) * LOG2E;
        }
    } else {
        int i = (blockIdx.x - 257) * 256 + threadIdx.x;
        if (i < NN) cnt[i] = 0;
    }
}

// ---- MFMA MLP (R0-proven binary: VGPR 100, ~70us; source kept as-is) ----
__device__ __forceinline__ void mlp_load(const float* const* xptr,
                                         const unsigned short* const* bptr,
                                         int koff, float4 (&ar)[4][2],
                                         short8 (&bc)[4]) {
#pragma unroll
    for (int mt = 0; mt < 4; ++mt) {
        ar[mt][0] = *(const float4*)(xptr[mt] + koff);
        ar[mt][1] = *(const float4*)(xptr[mt] + koff + 4);
    }
#pragma unroll
    for (int nt = 0; nt < 4; ++nt) bc[nt] = *(const short8*)(bptr[nt] + koff);
}

__device__ __forceinline__ void mlp_step(const float4 (&ar)[4][2],
                                         const short8 (&bc)[4],
                                         f32x4 (&acc)[4][4]) {
    short8 af[4];
#pragma unroll
    for (int mt = 0; mt < 4; ++mt) {
        union { short8 s; __hip_bfloat162 h[4]; } cv;
        cv.h[0] = __float22bfloat162_rn(make_float2(ar[mt][0].x, ar[mt][0].y));
        cv.h[1] = __float22bfloat162_rn(make_float2(ar[mt][0].z, ar[mt][0].w));
        cv.h[2] = __float22bfloat162_rn(make_float2(ar[mt][1].x, ar[mt][1].y));
        cv.h[3] = __float22bfloat162_rn(make_float2(ar[mt][1].z, ar[mt][1].w));
        af[mt] = cv.s;
    }
#pragma unroll
    for (int mt = 0; mt < 4; ++mt)
#pragma unroll
        for (int nt = 0; nt < 4; ++nt)
            acc[mt][nt] = __builtin_amdgcn_mfma_f32_16x16x32_bf16(
                af[mt], bc[nt], acc[mt][nt], 0, 0, 0);
}

__global__ __launch_bounds__(256) void mlp_mfma_kernel(
    const float* __restrict__ x, const unsigned short* __restrict__ W1t,
    const float* __restrict__ b1, const float* __restrict__ W2,
    const float* __restrict__ b2, float* __restrict__ logb0) {
    __shared__ unsigned short hs[128 * 136];
    __shared__ float W2s[128 * 8];
    __shared__ float b1s[128];
    __shared__ float b2s[8];

    const int tid = threadIdx.x;
    const int wave = tid >> 6;
    const int lane = tid & 63;
    const int q = lane >> 4;
    const int lm = lane & 15;
    const int wm = wave >> 1, wn = wave & 1;
    const int n0 = blockIdx.x * 128;

    if (tid < 128) b1s[tid] = b1[tid];
    if (tid < 8) b2s[tid] = b2[tid];
    {
        int i = tid * 4;
        *(float4*)&W2s[i] = *(const float4*)&W2[i];
    }
    __syncthreads();

    const float* xptr[4];
#pragma unroll
    for (int mt = 0; mt < 4; ++mt) {
        int r = n0 + wm * 64 + mt * 16 + lm;
        if (r > NN - 1) r = NN - 1;
        xptr[mt] = x + (size_t)r * DINK + q * 8;
    }
    const unsigned short* bptr[4];
#pragma unroll
    for (int nt = 0; nt < 4; ++nt) {
        int c = wn * 64 + nt * 16 + lm;
        bptr[nt] = W1t + (size_t)c * DINK + q * 8;
    }

    f32x4 acc[4][4];
#pragma unroll
    for (int mt = 0; mt < 4; ++mt)
#pragma unroll
        for (int nt = 0; nt < 4; ++nt) acc[mt][nt] = (f32x4){0.f, 0.f, 0.f, 0.f};

    float4 arA[4][2], arB[4][2];
    short8 bcA[4], bcB[4];
    mlp_load(xptr, bptr, 0, arA, bcA);
    mlp_load(xptr, bptr, 32, arB, bcB);

#pragma unroll
    for (int k0 = 0; k0 < DINK; k0 += 64) {
        mlp_step(arA, bcA, acc);
        if (k0 + 64 < DINK) mlp_load(xptr, bptr, k0 + 64, arA, bcA);
        mlp_step(arB, bcB, acc);
        if (k0 + 96 < DINK) mlp_load(xptr, bptr, k0 + 96, arB, bcB);
    }

#pragma unroll
    for (int nt = 0; nt < 4; ++nt) {
        int j = wn * 64 + nt * 16 + lm;
        float bj = b1s[j];
#pragma unroll
        for (int mt = 0; mt < 4; ++mt) {
            int rbase = wm * 64 + mt * 16 + q * 4;
#pragma unroll
            for (int r = 0; r < 4; ++r) {
                float h = fmaxf(acc[mt][nt][r] + bj, 0.0f);
                hs[(rbase + r) * 136 + j] = f2bf(h);
            }
        }
    }
    __syncthreads();

    int row = tid >> 1;
    int half = tid & 1;
    const unsigned short* hp = &hs[row * 136 + half * 64];
    float p[8] = {0.f, 0.f, 0.f, 0.f, 0.f, 0.f, 0.f, 0.f};
#pragma unroll
    for (int ch = 0; ch < 8; ++ch) {
        uint4 c4 = *(const uint4*)(hp + ch * 8);
        unsigned int uu[4] = {c4.x, c4.y, c4.z, c4.w};
#pragma unroll
        for (int p2 = 0; p2 < 4; ++p2) {
            float h0 = bfu2f(uu[p2] & 0xFFFFu);
            float h1 = bfu2f(uu[p2] >> 16);
            int j = half * 64 + ch * 8 + p2 * 2;
            const float* w0 = &W2s[j * 8];
            const float* w1 = &W2s[(j + 1) * 8];
#pragma unroll
            for (int c = 0; c < 8; ++c) p[c] = fmaf(h0, w0[c], p[c]);
#pragma unroll
            for (int c = 0; c < 8; ++c) p[c] = fmaf(h1, w1[c], p[c]);
        }
    }
#pragma unroll
    for (int c = 0; c < 8; ++c) p[c] += __shfl_xor(p[c], 1, 64);
    int grow = n0 + row;
    if (half == 0 && grow < NN) {
        float v[8];
        float mx = -1e30f;
#pragma unroll
        for (int c = 0; c < 8; ++c) {
            v[c] = p[c] + b2s[c];
            mx = fmaxf(mx, v[c]);
        }
        float s = 0.0f;
#pragma unroll
        for (int c = 0; c < 8; ++c) s += expf(v[c] - mx);
        float ln = mx + logf(s);
        float4* p0 = (float4*)&logb0[(size_t)grow * 8];
        p0[0] = make_float4(v[0] - ln, v[1] - ln, v[2] - ln, v[3] - ln);
        p0[1] = make_float4(v[4] - ln, v[5] - ln, v[6] - ln, v[7] - ln);
    }
}

// ---------------- CSR setup ----------------

__global__ __launch_bounds__(256) void deg_pair_kernel(const int* __restrict__ ei,
                                                       int* __restrict__ cnt) {
    int e = blockIdx.x * 256 + threadIdx.x;
    if (e >= E2K) return;
    int s = ei[e];
    int d = ei[EE + e];
    atomicAdd(&cnt[d], 1);
    atomicAdd(&cnt[s], 1);
}

__global__ __launch_bounds__(256) void scan_partial_kernel(
    const int* __restrict__ cnt, int* __restrict__ partial) {
    __shared__ int sd[256];
    int t = threadIdx.x;
    int i = blockIdx.x * 256 + t;
    sd[t] = (i < NN) ? cnt[i] : 0;
    __syncthreads();
#pragma unroll
    for (int s = 128; s > 0; s >>= 1) {
        if (t < s) sd[t] += sd[t + s];
        __syncthreads();
    }
    if (t == 0) partial[blockIdx.x] = sd[0];
}

__global__ __launch_bounds__(256) void scan_write2_kernel(
    const int* __restrict__ cnt, const int* __restrict__ partial,
    int* __restrict__ off, int* __restrict__ cnt_z) {
    __shared__ int sd[256];
    const int t = threadIdx.x;
    const int b = blockIdx.x;
    sd[t] = (t < NBLKS) ? partial[t] : 0;
    __syncthreads();
#pragma unroll
    for (int s = 1; s < 256; s <<= 1) {
        int a = sd[t];
        int v = (t >= s) ? sd[t - s] : 0;
        __syncthreads();
        sd[t] = a + v;
        __syncthreads();
    }
    const int top = (b > 0) ? sd[b - 1] : 0;
    __syncthreads();
    int i = b * 256 + t;
    int v = (i < NN) ? cnt[i] : 0;
    sd[t] = v;
    __syncthreads();
#pragma unroll
    for (int s = 1; s < 256; s <<= 1) {
        int a = sd[t];
        int w = (t >= s) ? sd[t - s] : 0;
        __syncthreads();
        sd[t] = a + w;
        __syncthreads();
    }
    if (i < NN) {
        off[i] = top + sd[t] - v;
        cnt_z[i] = 0;
    }
    if (i == NN - 1) off[NN] = EE;
}

// merged: blocks [0,E2B) place edges (rw = (rvp, wbits)); blocks [E2B, ...)
// init z0[j] = fp16(logb0[dst(j)] * LOG2E) contiguously per CSR slice.
__global__ __launch_bounds__(256) void pos_zinit_kernel(
    const int* __restrict__ ei, const float* __restrict__ ew,
    const int* __restrict__ off, int* __restrict__ cnt,
    int2* __restrict__ rw, const float* __restrict__ logb0,
    _Float16* __restrict__ z, int E2B) {
    const int t = threadIdx.x;
    if ((int)blockIdx.x < E2B) {
        int e = blockIdx.x * 256 + t;
        if (e >= E2K) return;
        int s = ei[e];
        int d = ei[EE + e];
        int wbits = __float_as_int(ew[e]);
        int pA = off[d] + atomicAdd(&cnt[d], 1);  // edge e: s->d
        int pB = off[s] + atomicAdd(&cnt[s], 1);  // edge e+E2: d->s
        int2 v;
        v.x = pB; v.y = wbits; rw[pA] = v;
        v.x = pA;              rw[pB] = v;
    } else {
        int b = blockIdx.x - E2B;
        int n = b * 32 + (t >> 3);
        int c = t & 7;
        if (n >= NN) return;
        _Float16 v = (_Float16)(logb0[(size_t)n * 8 + c] * LOG2E);
        int j0 = off[n];
        int j1 = off[n + 1];
        for (int j = j0; j < j1; ++j) z[(size_t)j * 8 + c] = v;
    }
}

// ---------------- fused BP iteration: ONE dispatch per iteration ------------
// ALL BP math in log2 domain: v_exp_f32/v_log_f32 natively compute 2^x /
// log2(x), so the natural-log domain's hidden x1.4427 multiply per
// transcendental (64 mul + 8 mul per edge) is deleted. lH pre-scaled in prep,
// logb0 scaled at node granularity, output scaled back by LN2 on last iter.
__global__ __launch_bounds__(256) void bp_fused_kernel(
    const float* __restrict__ logb0, const int* __restrict__ off,
    const int2* __restrict__ rw, const float* __restrict__ logH,
    const uint4* __restrict__ zprev, _Float16* __restrict__ znext,
    float* __restrict__ out, int last) {
    __shared__ _Float16 smg[CAP * 8];   // 16 KB message cache
    __shared__ float sb[NPB * 8];       // beliefs (log2 units)
    __shared__ unsigned char dln[CAP];  // j-cb -> local node
    __shared__ float lH[64];
    const int t = threadIdx.x;
    if (t < 64) lH[t] = logH[t];

    const int n0 = blockIdx.x * NPB;
    const int nend = (n0 + NPB < NN) ? (n0 + NPB) : NN;
    const int jb0 = off[n0];
    const int jb1 = off[nend];
    const int nl = t >> 3;
    const int c = t & 7;
    const int n = n0 + nl;

    float a = 0.0f;
    int jn0 = 0, jn1 = 0;
    if (n < nend) {
        jn0 = off[n];
        jn1 = off[n + 1];
        a = logb0[(size_t)n * 8 + c] * LOG2E;
    }
    __syncthreads();  // lH ready

    const int single = (jb1 - jb0) <= CAP;

    for (int cb = jb0; cb < jb1; cb += CAP) {
        int ce = (cb + CAP < jb1) ? (cb + CAP) : jb1;
        for (int j = cb + t; j < ce; j += 256) {
            int2 h = rw[j];
            uint4 zv = zprev[h.x];  // single random 16B gather
            float w = __int_as_float(h.y);
            union { uint4 u; _Float16 hh[8]; } cv;
            cv.u = zv;
            float xj[8];
#pragma unroll
            for (int k = 0; k < 8; ++k) xj[k] = (float)cv.hh[k];
            float mg[8];
#pragma unroll
            for (int c2 = 0; c2 < 8; ++c2) {
                float ssum = 0.0f;
#pragma unroll
                for (int c1 = 0; c1 < 8; ++c1)
                    ssum += __builtin_amdgcn_exp2f(
                        fmaf(w, lH[c1 * 8 + c2], xj[c1]));
                mg[c2] = __builtin_amdgcn_logf(ssum);
            }
            union { uint4 u; _Float16 hh[8]; } ov;
#pragma unroll
            for (int k = 0; k < 8; ++k) ov.hh[k] = (_Float16)mg[k];
            *(uint4*)&smg[(j - cb) * 8] = ov.u;
        }
        __syncthreads();
        int lo = (jn0 > cb) ? jn0 : cb;
        int hi = (jn1 < ce) ? jn1 : ce;
        for (int j = lo; j < hi; ++j) {
            a += (float)smg[(j - cb) * 8 + c];
            if (c == 0) dln[j - cb] = (unsigned char)nl;
        }
        __syncthreads();  // protect smg before next chunk
    }

    // ---- normalize belief (8-thread groups, log2 domain) ----
    float mx = a;
#pragma unroll
    for (int s = 1; s < 8; s <<= 1) mx = fmaxf(mx, __shfl_xor(mx, s, 8));
    float sum = __builtin_amdgcn_exp2f(a - mx);
#pragma unroll
    for (int s = 1; s < 8; s <<= 1) sum += __shfl_xor(sum, s, 8);
    float v = a - (mx + __builtin_amdgcn_logf(sum));
    if (n < nend) {
        if (last) out[(size_t)n * 8 + c] = v * LN2;
        sb[nl * 8 + c] = v;
    }
    if (last) return;
    __syncthreads();

    // ---- z-write: contiguous, load-balanced over (edge, channel) items ----
    for (int cb = jb0; cb < jb1; cb += CAP) {
        int ce = (cb + CAP < jb1) ? (cb + CAP) : jb1;
        if (!single) {
            // rare path: recompute this chunk's messages + rebuild dln
            for (int j = cb + t; j < ce; j += 256) {
                int2 h = rw[j];
                uint4 zv = zprev[h.x];
                float w = __int_as_float(h.y);
                union { uint4 u; _Float16 hh[8]; } cv;
                cv.u = zv;
                float xj[8];
#pragma unroll
                for (int k = 0; k < 8; ++k) xj[k] = (float)cv.hh[k];
                float mg[8];
#pragma unroll
                for (int c2 = 0; c2 < 8; ++c2) {
                    float ssum = 0.0f;
#pragma unroll
                    for (int c1 = 0; c1 < 8; ++c1)
                        ssum += __builtin_amdgcn_exp2f(
                            fmaf(w, lH[c1 * 8 + c2], xj[c1]));
                    mg[c2] = __builtin_amdgcn_logf(ssum);
                }
                union { uint4 u; _Float16 hh[8]; } ov;
#pragma unroll
                for (int k = 0; k < 8; ++k) ov.hh[k] = (_Float16)mg[k];
                *(uint4*)&smg[(j - cb) * 8] = ov.u;
            }
            if (c == 0) {
                int lo = (jn0 > cb) ? jn0 : cb;
                int hi = (jn1 < ce) ? jn1 : ce;
                for (int j = lo; j < hi; ++j) dln[j - cb] = (unsigned char)nl;
            }
            __syncthreads();
        }
        int items = (ce - cb) * 8;
        for (int item = t; item < items; item += 256) {
            int jr = item >> 3;
            int c2 = item & 7;
            int dl = dln[jr];
            znext[(size_t)(cb + jr) * 8 + c2] =
                (_Float16)(sb[dl * 8 + c2] - (float)smg[jr * 8 + c2]);
        }
        if (!single) __syncthreads();
    }
}

extern "C" void kernel_launch(void* const* d_in, const int* in_sizes, int n_in,
                              void* d_out, int out_size, void* d_ws, size_t ws_size,
                              hipStream_t stream) {
    const float* x = (const float*)d_in[0];
    const int* ei = (const int*)d_in[1];
    const float* ew = (const float*)d_in[2];
    const float* W1 = (const float*)d_in[4];
    const float* b1 = (const float*)d_in[5];
    const float* W2 = (const float*)d_in[6];
    const float* b2 = (const float*)d_in[7];
    const float* param = (const float*)d_in[8];
    float* out = (float*)d_out;

    float* wsf = (float*)d_ws;
    float* logH = wsf;                                 // 64 f (log2 units)
    float* logb0 = logH + 64;                          // 400000 f (natural)
    uint4* zA = (uint4*)(logb0 + (size_t)NN * 8);      // 12.8 MB (log2 units)
    uint4* zB = zA + EE;                               // 12.8 MB
    int* off = (int*)(zB + EE);                        // padded to 50004 ints
    int2* rw = (int2*)(off + 50004);                   // 800000 int2
    unsigned short* W1t = (unsigned short*)(rw + EE);  // 65536 bf16
    // setup-only scratch aliases zB (zB first written by bp iter 0; zA is
    // written by zinit which runs concurrently with pos -> must not alias zA)
    int* cnt = (int*)zB;                               // 50000
    int* partial = cnt + NN;                           // 196

    const int ZB_ = (NN + 255) / 256;  // cnt-zero blocks in prep
    prep_kernel<<<257 + ZB_, 256, 0, stream>>>(W1, param, W1t, logH, cnt);
    mlp_mfma_kernel<<<(NN + 127) / 128, 256, 0, stream>>>(x, W1t, b1, W2, b2,
                                                          logb0);

    const int E2B = (E2K + 255) / 256;  // 1563
    const int AB = (NN + 31) / 32;      // 1563
    deg_pair_kernel<<<E2B, 256, 0, stream>>>(ei, cnt);
    scan_partial_kernel<<<NBLKS, 256, 0, stream>>>(cnt, partial);
    scan_write2_kernel<<<NBLKS, 256, 0, stream>>>(cnt, partial, off, cnt);
    pos_zinit_kernel<<<E2B + AB, 256, 0, stream>>>(ei, ew, off, cnt, rw, logb0,
                                                   (_Float16*)zA, E2B);

    // z ping-pong: zinit->zA; it0 zA->zB; it1 zB->zA; ... it4 reads zA
    const int BB = (NN + NPB - 1) / NPB;  // 1563
    uint4* zs[2] = {zA, zB};
    for (int it = 0; it < KIT; ++it) {
        bp_fused_kernel<<<BB, 256, 0, stream>>>(
            logb0, off, rw, logH, zs[it & 1], (_Float16*)zs[(it + 1) & 1], out,
            it == KIT - 1 ? 1 : 0);
    }
}